// Round 1
// baseline (503.305 us; speedup 1.0000x reference)
//
#include <hip/hip_runtime.h>
#include <hip/hip_cooperative_groups.h>
#include <math.h>

namespace cg = cooperative_groups;

// LRU scan: h[b,t,d] = lam[d]*h[b,t-1,d] + gam[d]*x[b,t,d], inclusive over t.
// lam = exp(-exp(nu_logs)), gam = sqrt(1-lam^2).
// FUSED single cooperative kernel (was 3 dispatches):
//   phase1: per-chunk aggregate (h=0 seed) -> carry[b,c,d]    (reads x once, cold)
//   grid.sync()
//   phase2: parallel Kogge-Stone scan of carries along c (same 1024 blocks,
//           re-mapped to (b,d4) columns; decay per chunk is uniform lam^L,
//           step-k weight lam^(L*2^k) via iterative squaring; 8 LDS steps)
//   grid.sync()
//   phase3: seeded per-chunk scan, re-reads x (L3-hot), writes out with
//           NON-TEMPORAL stores so the out stream doesn't evict x from L3.
// Fusion keeps lam/gam in registers across phases and removes 2 launch
// boundaries + the phase2 full-grid stall.

#define B_  4
#define I_  8192
#define D_  1024
#define C_  256           // chunks along time
#define L_  32            // I_ / C_
#define D4  (D_ / 4)      // float4 groups along d

typedef float f32x4 __attribute__((ext_vector_type(4)));

// grid = B_*C_ = 1024 blocks of 256 threads = 4 blocks/CU * 256 CU exactly
// co-resident at launch_bounds(256,4) (VGPR capped at 128).
__global__ __launch_bounds__(256, 4) void lru_fused(
        const float4* __restrict__ x,
        const float* __restrict__ nu_logs,
        float4* __restrict__ carry,
        float4* __restrict__ out) {
    cg::grid_group grid = cg::this_grid();
    __shared__ float4 buf[C_];                    // 4 KiB, phase2 only

    const int blk = blockIdx.x;                   // 0..1023
    const int d4  = threadIdx.x;                  // phase1/3: d4 lane (coalesced)
    const int c   = blk & (C_ - 1);
    const int b   = blk >> 8;

    // lam/gam for phase 1/3 (indexed by threadIdx) — live across all phases.
    const float* nl = nu_logs + d4 * 4;
    float4 lam, gam;
    lam.x = expf(-expf(nl[0]));
    lam.y = expf(-expf(nl[1]));
    lam.z = expf(-expf(nl[2]));
    lam.w = expf(-expf(nl[3]));
    gam.x = sqrtf(1.0f - lam.x * lam.x);
    gam.y = sqrtf(1.0f - lam.y * lam.y);
    gam.z = sqrtf(1.0f - lam.z * lam.z);
    gam.w = sqrtf(1.0f - lam.w * lam.w);

    // ---------------- phase 1: chunk aggregates ----------------
    {
        float4 h = {0.f, 0.f, 0.f, 0.f};
        int idx = (b * I_ + c * L_) * D4 + d4;
#pragma unroll 8
        for (int t = 0; t < L_; ++t) {
            float4 v = x[idx];
            h.x = fmaf(lam.x, h.x, gam.x * v.x);
            h.y = fmaf(lam.y, h.y, gam.y * v.y);
            h.z = fmaf(lam.z, h.z, gam.z * v.z);
            h.w = fmaf(lam.w, h.w, gam.w * v.w);
            idx += D4;
        }
        carry[(b * C_ + c) * D4 + d4] = h;
    }

    grid.sync();

    // ---------------- phase 2: weighted Kogge-Stone over c ----------------
    // Re-map: block = (b2, dd) column, threads = chunk index c2.
    {
        const int c2 = threadIdx.x;
        const int dd = blk & (D4 - 1);
        const int b2 = blk >> 8;

        // nu_logs reads are block-uniform here -> scalar loads.
        const float* nl2 = nu_logs + dd * 4;
        float4 p;                                 // lam^L, then squared per step
        p.x = expf(-expf(nl2[0]) * (float)L_);
        p.y = expf(-expf(nl2[1]) * (float)L_);
        p.z = expf(-expf(nl2[2]) * (float)L_);
        p.w = expf(-expf(nl2[3]) * (float)L_);

        const int gidx = (b2 * C_ + c2) * D4 + dd;
        float4 val = carry[gidx];
        buf[c2] = val;

        for (int off = 1; off < C_; off <<= 1) {
            __syncthreads();
            float4 prev = (c2 >= off) ? buf[c2 - off]
                                      : make_float4(0.f, 0.f, 0.f, 0.f);
            __syncthreads();
            if (c2 >= off) {
                val.x = fmaf(p.x, prev.x, val.x);
                val.y = fmaf(p.y, prev.y, val.y);
                val.z = fmaf(p.z, prev.z, val.z);
                val.w = fmaf(p.w, prev.w, val.w);
                buf[c2] = val;
            }
            p.x *= p.x; p.y *= p.y; p.z *= p.z; p.w *= p.w;
        }
        __syncthreads();
        // exclusive carry for chunk c2 = inclusive prefix of chunk c2-1
        float4 excl = (c2 == 0) ? make_float4(0.f, 0.f, 0.f, 0.f) : buf[c2 - 1];
        carry[gidx] = excl;
    }

    grid.sync();

    // ---------------- phase 3: seeded scan, write out ----------------
    {
        float4 h = carry[(b * C_ + c) * D4 + d4];
        int idx = (b * I_ + c * L_) * D4 + d4;
#pragma unroll 8
        for (int t = 0; t < L_; ++t) {
            float4 v = x[idx];                    // L3-hot re-read
            h.x = fmaf(lam.x, h.x, gam.x * v.x);
            h.y = fmaf(lam.y, h.y, gam.y * v.y);
            h.z = fmaf(lam.z, h.z, gam.z * v.z);
            h.w = fmaf(lam.w, h.w, gam.w * v.w);
            // non-temporal: don't let the out stream evict x from L3
            __builtin_nontemporal_store(*(const f32x4*)&h, (f32x4*)&out[idx]);
            idx += D4;
        }
    }
}

extern "C" void kernel_launch(void* const* d_in, const int* in_sizes, int n_in,
                              void* d_out, int out_size, void* d_ws, size_t ws_size,
                              hipStream_t stream) {
    (void)in_sizes; (void)n_in; (void)out_size; (void)ws_size;
    const float4* x       = (const float4*)d_in[0];   // [B, I, D] fp32
    const float*  nu_logs = (const float*)d_in[1];    // [D] fp32
    float4*       out     = (float4*)d_out;           // [B, I, D] fp32
    float4*       carry   = (float4*)d_ws;            // B_*C_*D_ floats = 4 MiB

    void* args[] = {(void*)&x, (void*)&nu_logs, (void*)&carry, (void*)&out};
    hipLaunchCooperativeKernel((void*)lru_fused, dim3(B_ * C_), dim3(256),
                               args, 0, stream);
}

// Round 2
// 266.782 us; speedup vs baseline: 1.8866x; 1.8866x over previous
//
#include <hip/hip_runtime.h>
#include <math.h>

// LRU scan: h[b,t,d] = lam[d]*h[b,t-1,d] + gam[d]*x[b,t,d], inclusive over t.
// lam = exp(-exp(nu_logs)), gam = sqrt(1-lam^2).
//
// 2-kernel chunked scan (cooperative fusion REGRESSED 2x in round 1 —
// grid.sync() path ran every byte at ~900 GB/s; reverted):
//   K1 lru_carry:    per-chunk aggregate with h=0 seed -> carry[b,c,d]
//                    (reads x once, cold from HBM)
//   K2 lru_scan_out: per-block Horner reduction over carries replaces the
//                    old phase-2 scan kernel (block (b,c) only needs ITS
//                    exclusive prefix = weighted sum of carries j<c; carry
//                    is 4 MiB -> L2-hot), then seeded chunk scan writes out.
//                    x re-read is L3-hot (proved by round-1 FETCH_SIZE).
// Both kernels stage 8 independent float4 loads ahead of the serial FMA
// chain (round-0/1 builds had VGPR=32 => <=4 loads in flight).

#define B_  4
#define I_  8192
#define D_  1024
#define C_  256           // chunks along time
#define L_  32            // I_ / C_
#define D4  (D_ / 4)      // float4 groups along d

__device__ __forceinline__ void load_lam_gam(const float* __restrict__ nu_logs,
                                             int d4, float4& lam, float4& gam) {
    const float* nl = nu_logs + d4 * 4;
    lam.x = expf(-expf(nl[0]));
    lam.y = expf(-expf(nl[1]));
    lam.z = expf(-expf(nl[2]));
    lam.w = expf(-expf(nl[3]));
    gam.x = sqrtf(1.0f - lam.x * lam.x);
    gam.y = sqrtf(1.0f - lam.y * lam.y);
    gam.z = sqrtf(1.0f - lam.z * lam.z);
    gam.w = sqrtf(1.0f - lam.w * lam.w);
}

__device__ __forceinline__ void step(float4& h, const float4 lam,
                                     const float4 gam, const float4 v) {
    h.x = fmaf(lam.x, h.x, gam.x * v.x);
    h.y = fmaf(lam.y, h.y, gam.y * v.y);
    h.z = fmaf(lam.z, h.z, gam.z * v.z);
    h.w = fmaf(lam.w, h.w, gam.w * v.w);
}

// ---------------- K1: per-chunk aggregates ----------------
__global__ __launch_bounds__(256) void lru_carry(const float4* __restrict__ x,
                                                 const float* __restrict__ nu_logs,
                                                 float4* __restrict__ carry) {
    int tid = blockIdx.x * 256 + threadIdx.x;     // 0 .. B_*C_*D4-1
    int d4 = tid & (D4 - 1);                      // consecutive lanes -> coalesced
    int c  = (tid >> 8) & (C_ - 1);
    int b  = tid >> 16;

    float4 lam, gam;
    load_lam_gam(nu_logs, d4, lam, gam);

    int idx = (b * I_ + c * L_) * D4 + d4;
    float4 h = {0.f, 0.f, 0.f, 0.f};
#pragma unroll
    for (int tt = 0; tt < L_; tt += 8) {
        // 8 independent loads in flight before the serial chain
        float4 v0 = x[idx + 0 * D4];
        float4 v1 = x[idx + 1 * D4];
        float4 v2 = x[idx + 2 * D4];
        float4 v3 = x[idx + 3 * D4];
        float4 v4 = x[idx + 4 * D4];
        float4 v5 = x[idx + 5 * D4];
        float4 v6 = x[idx + 6 * D4];
        float4 v7 = x[idx + 7 * D4];
        step(h, lam, gam, v0);
        step(h, lam, gam, v1);
        step(h, lam, gam, v2);
        step(h, lam, gam, v3);
        step(h, lam, gam, v4);
        step(h, lam, gam, v5);
        step(h, lam, gam, v6);
        step(h, lam, gam, v7);
        idx += 8 * D4;
    }
    carry[(b * C_ + c) * D4 + d4] = h;
}

// ---------------- K2: carry-prefix prologue + seeded scan + out ----------------
__global__ __launch_bounds__(256) void lru_scan_out(const float4* __restrict__ x,
                                                    const float* __restrict__ nu_logs,
                                                    const float4* __restrict__ carry,
                                                    float4* __restrict__ out) {
    int tid = blockIdx.x * 256 + threadIdx.x;
    int d4 = tid & (D4 - 1);
    int c  = (tid >> 8) & (C_ - 1);               // block-uniform chunk index
    int b  = tid >> 16;

    float4 lam, gam;
    load_lam_gam(nu_logs, d4, lam, gam);

    // pL = lam^L  (uniform chunk decay)
    const float* nl = nu_logs + d4 * 4;
    float4 pL;
    pL.x = expf(-expf(nl[0]) * (float)L_);
    pL.y = expf(-expf(nl[1]) * (float)L_);
    pL.z = expf(-expf(nl[2]) * (float)L_);
    pL.w = expf(-expf(nl[3]) * (float)L_);

    // Exclusive prefix for this chunk via Horner over carries j = 0..c-1:
    //   h = sum_{j<c} pL^(c-1-j) * carry[b,j,d4]
    // Loop length c is block-uniform (no divergence); carry is L2-hot.
    float4 h = {0.f, 0.f, 0.f, 0.f};
    const float4* cb = carry + b * C_ * D4 + d4;
#pragma unroll 4
    for (int j = 0; j < c; ++j) {
        float4 cj = cb[j * D4];
        h.x = fmaf(pL.x, h.x, cj.x);
        h.y = fmaf(pL.y, h.y, cj.y);
        h.z = fmaf(pL.z, h.z, cj.z);
        h.w = fmaf(pL.w, h.w, cj.w);
    }

    // Seeded chunk scan, write out (x re-read is L3-hot).
    int idx = (b * I_ + c * L_) * D4 + d4;
#pragma unroll
    for (int tt = 0; tt < L_; tt += 8) {
        float4 v0 = x[idx + 0 * D4];
        float4 v1 = x[idx + 1 * D4];
        float4 v2 = x[idx + 2 * D4];
        float4 v3 = x[idx + 3 * D4];
        float4 v4 = x[idx + 4 * D4];
        float4 v5 = x[idx + 5 * D4];
        float4 v6 = x[idx + 6 * D4];
        float4 v7 = x[idx + 7 * D4];
        step(h, lam, gam, v0); out[idx + 0 * D4] = h;
        step(h, lam, gam, v1); out[idx + 1 * D4] = h;
        step(h, lam, gam, v2); out[idx + 2 * D4] = h;
        step(h, lam, gam, v3); out[idx + 3 * D4] = h;
        step(h, lam, gam, v4); out[idx + 4 * D4] = h;
        step(h, lam, gam, v5); out[idx + 5 * D4] = h;
        step(h, lam, gam, v6); out[idx + 6 * D4] = h;
        step(h, lam, gam, v7); out[idx + 7 * D4] = h;
        idx += 8 * D4;
    }
}

extern "C" void kernel_launch(void* const* d_in, const int* in_sizes, int n_in,
                              void* d_out, int out_size, void* d_ws, size_t ws_size,
                              hipStream_t stream) {
    (void)in_sizes; (void)n_in; (void)out_size; (void)ws_size;
    const float4* x       = (const float4*)d_in[0];   // [B, I, D] fp32
    const float*  nu_logs = (const float*)d_in[1];    // [D] fp32
    float4*       out     = (float4*)d_out;           // [B, I, D] fp32
    float4*       carry   = (float4*)d_ws;            // B_*C_*D_ floats = 4 MiB

    dim3 blk(256);
    dim3 grd((B_ * C_ * D4) / 256);                   // 1024 blocks

    lru_carry<<<grd, blk, 0, stream>>>(x, nu_logs, carry);
    lru_scan_out<<<grd, blk, 0, stream>>>(x, nu_logs, carry, out);
}

// Round 3
// 265.636 us; speedup vs baseline: 1.8947x; 1.0043x over previous
//
#include <hip/hip_runtime.h>
#include <math.h>

// LRU scan: h[b,t,d] = lam[d]*h[b,t-1,d] + gam[d]*x[b,t,d], inclusive over t.
// lam = exp(-exp(nu_logs)), gam = sqrt(1-lam^2).
//
// 2-kernel chunked scan. History:
//  - cooperative fusion (R1): 2x REGRESSION (grid.sync path ~900 GB/s). reverted.
//  - R2 (this structure, plain stores, Horner not overlapped): 266.8 us total,
//    K1+K2 ~= 99 us vs ~55 us floor.
// R3 changes, both K2-only:
//  - NON-TEMPORAL out stores: footprint x+out+carry = 260 MiB > 256 MiB L3,
//    plain stores evict x before the re-read. R1's FETCH=150MB with NT stores
//    proved the re-read stays L3-hot when out bypasses.
//  - Overlap the Horner carry-prefix with the first 8 x loads + software-
//    pipeline the scan loop (prefetch next 8 while consuming 8). Previously
//    the HBM pipes idled during the ~10us Horner prologue.

#define B_  4
#define I_  8192
#define D_  1024
#define C_  256           // chunks along time
#define L_  32            // I_ / C_
#define D4  (D_ / 4)      // float4 groups along d

typedef float f32x4 __attribute__((ext_vector_type(4)));

__device__ __forceinline__ void load_lam_gam(const float* __restrict__ nu_logs,
                                             int d4, float4& lam, float4& gam) {
    const float* nl = nu_logs + d4 * 4;
    lam.x = expf(-expf(nl[0]));
    lam.y = expf(-expf(nl[1]));
    lam.z = expf(-expf(nl[2]));
    lam.w = expf(-expf(nl[3]));
    gam.x = sqrtf(1.0f - lam.x * lam.x);
    gam.y = sqrtf(1.0f - lam.y * lam.y);
    gam.z = sqrtf(1.0f - lam.z * lam.z);
    gam.w = sqrtf(1.0f - lam.w * lam.w);
}

__device__ __forceinline__ void step(float4& h, const float4 lam,
                                     const float4 gam, const float4 v) {
    h.x = fmaf(lam.x, h.x, gam.x * v.x);
    h.y = fmaf(lam.y, h.y, gam.y * v.y);
    h.z = fmaf(lam.z, h.z, gam.z * v.z);
    h.w = fmaf(lam.w, h.w, gam.w * v.w);
}

// ---------------- K1: per-chunk aggregates ----------------
__global__ __launch_bounds__(256) void lru_carry(const float4* __restrict__ x,
                                                 const float* __restrict__ nu_logs,
                                                 float4* __restrict__ carry) {
    int tid = blockIdx.x * 256 + threadIdx.x;     // 0 .. B_*C_*D4-1
    int d4 = tid & (D4 - 1);                      // consecutive lanes -> coalesced
    int c  = (tid >> 8) & (C_ - 1);
    int b  = tid >> 16;

    float4 lam, gam;
    load_lam_gam(nu_logs, d4, lam, gam);

    int idx = (b * I_ + c * L_) * D4 + d4;
    float4 h = {0.f, 0.f, 0.f, 0.f};
#pragma unroll
    for (int tt = 0; tt < L_; tt += 8) {
        float4 v0 = x[idx + 0 * D4];
        float4 v1 = x[idx + 1 * D4];
        float4 v2 = x[idx + 2 * D4];
        float4 v3 = x[idx + 3 * D4];
        float4 v4 = x[idx + 4 * D4];
        float4 v5 = x[idx + 5 * D4];
        float4 v6 = x[idx + 6 * D4];
        float4 v7 = x[idx + 7 * D4];
        step(h, lam, gam, v0);
        step(h, lam, gam, v1);
        step(h, lam, gam, v2);
        step(h, lam, gam, v3);
        step(h, lam, gam, v4);
        step(h, lam, gam, v5);
        step(h, lam, gam, v6);
        step(h, lam, gam, v7);
        idx += 8 * D4;
    }
    carry[(b * C_ + c) * D4 + d4] = h;
}

// ---------------- K2: overlapped carry-prefix + pipelined scan + NT out ----------------
__global__ __launch_bounds__(256) void lru_scan_out(const float4* __restrict__ x,
                                                    const float* __restrict__ nu_logs,
                                                    const float4* __restrict__ carry,
                                                    float4* __restrict__ out) {
    int tid = blockIdx.x * 256 + threadIdx.x;
    int d4 = tid & (D4 - 1);
    int c  = (tid >> 8) & (C_ - 1);               // block-uniform chunk index
    int b  = tid >> 16;

    float4 lam, gam;
    load_lam_gam(nu_logs, d4, lam, gam);

    // pL = lam^L  (uniform chunk decay)
    const float* nl = nu_logs + d4 * 4;
    float4 pL;
    pL.x = expf(-expf(nl[0]) * (float)L_);
    pL.y = expf(-expf(nl[1]) * (float)L_);
    pL.z = expf(-expf(nl[2]) * (float)L_);
    pL.w = expf(-expf(nl[3]) * (float)L_);

    int idx = (b * I_ + c * L_) * D4 + d4;

    // Issue the first 8 x-tile loads BEFORE the Horner so HBM/L3 reads
    // complete underneath the L2-hot carry-prefix reduction.
    float4 v[8];
#pragma unroll
    for (int k = 0; k < 8; ++k) v[k] = x[idx + k * D4];

    // Exclusive prefix for this chunk via Horner over carries j = 0..c-1:
    //   h = sum_{j<c} pL^(c-1-j) * carry[b,j,d4]
    // Loop length c is block-uniform (no divergence); carry (4 MiB) is L2-hot.
    float4 h = {0.f, 0.f, 0.f, 0.f};
    const float4* cb = carry + b * C_ * D4 + d4;
#pragma unroll 4
    for (int j = 0; j < c; ++j) {
        float4 cj = cb[j * D4];
        h.x = fmaf(pL.x, h.x, cj.x);
        h.y = fmaf(pL.y, h.y, cj.y);
        h.z = fmaf(pL.z, h.z, cj.z);
        h.w = fmaf(pL.w, h.w, cj.w);
    }

    // Seeded chunk scan, software-pipelined (prefetch next 8 while consuming 8).
    // Fully unrolled -> all array indices compile-time (registers, no scratch).
    // NT stores: keep the out stream from evicting x out of L3.
#pragma unroll
    for (int tt = 0; tt < L_; tt += 8) {
        float4 w[8];
        if (tt + 8 < L_) {
#pragma unroll
            for (int k = 0; k < 8; ++k) w[k] = x[idx + (8 + k) * D4];
        }
#pragma unroll
        for (int k = 0; k < 8; ++k) {
            step(h, lam, gam, v[k]);
            __builtin_nontemporal_store(*(const f32x4*)&h, (f32x4*)&out[idx + k * D4]);
        }
        if (tt + 8 < L_) {
#pragma unroll
            for (int k = 0; k < 8; ++k) v[k] = w[k];
        }
        idx += 8 * D4;
    }
}

extern "C" void kernel_launch(void* const* d_in, const int* in_sizes, int n_in,
                              void* d_out, int out_size, void* d_ws, size_t ws_size,
                              hipStream_t stream) {
    (void)in_sizes; (void)n_in; (void)out_size; (void)ws_size;
    const float4* x       = (const float4*)d_in[0];   // [B, I, D] fp32
    const float*  nu_logs = (const float*)d_in[1];    // [D] fp32
    float4*       out     = (float4*)d_out;           // [B, I, D] fp32
    float4*       carry   = (float4*)d_ws;            // B_*C_*D_ floats = 4 MiB

    dim3 blk(256);
    dim3 grd((B_ * C_ * D4) / 256);                   // 1024 blocks

    lru_carry<<<grd, blk, 0, stream>>>(x, nu_logs, carry);
    lru_scan_out<<<grd, blk, 0, stream>>>(x, nu_logs, carry, out);
}